// Round 1
// baseline (3134.590 us; speedup 1.0000x reference)
//
#include <hip/hip_runtime.h>

#define B_ 4
#define S_ 4096
#define IN_ 1024
#define H_ 16
#define D_ 64
#define OUT_ 1024
#define HD_ 1024   // H*D
#define M_ 16384   // B*S

typedef __bf16 bf16x8 __attribute__((ext_vector_type(8)));
typedef float floatx4 __attribute__((ext_vector_type(4)));

static __device__ __forceinline__ unsigned short f2bf(float f) {
    unsigned int u = __builtin_bit_cast(unsigned int, f);
    u += 0x7fffu + ((u >> 16) & 1u);   // round-to-nearest-even
    return (unsigned short)(u >> 16);
}

// ---------------- cast fp32 -> bf16, vectorized x4 ----------------
__global__ void cast_f32_bf16(const float* __restrict__ src,
                              unsigned short* __restrict__ dst, int n4) {
    int i = blockIdx.x * blockDim.x + threadIdx.x;
    if (i < n4) {
        float4 v = ((const float4*)src)[i];
        ushort4 o;
        o.x = f2bf(v.x); o.y = f2bf(v.y); o.z = f2bf(v.z); o.w = f2bf(v.w);
        ((ushort4*)dst)[i] = o;
    }
}

// ---------------- bf16 MFMA GEMM: C[M,N] = A[M,K] * B[N,K]^T ----------------
// 128x128 tile, BK=32, 4 waves (2x2), each wave 64x64 = 4x4 MFMA 16x16x32 tiles.
// LDS padded to stride 40 elems (80B) to break bank conflicts on frag reads.
#define LSTR 40
__global__ __launch_bounds__(256) void gemm_bt(
    const unsigned short* __restrict__ A,   // [M,K] bf16
    const unsigned short* __restrict__ Bm,  // [N,K] bf16
    float* __restrict__ C, int M, int N, int K) {
    __shared__ unsigned short As[128 * LSTR];
    __shared__ unsigned short Bs[128 * LSTR];
    const int t = threadIdx.x;
    const int lane = t & 63;
    const int wave = t >> 6;
    const int wm = wave >> 1, wn = wave & 1;
    const int m0 = blockIdx.y * 128;
    const int n0 = blockIdx.x * 128;
    const int l16 = lane & 15;
    const int quad = lane >> 4;

    floatx4 acc[4][4];
#pragma unroll
    for (int i = 0; i < 4; i++)
#pragma unroll
        for (int j = 0; j < 4; j++) acc[i][j] = (floatx4){0.f, 0.f, 0.f, 0.f};

    for (int k0 = 0; k0 < K; k0 += 32) {
        // stage 128x32 of A and B: 512 chunks of 8 bf16 (16B) each
#pragma unroll
        for (int it = 0; it < 2; it++) {
            int c = it * 256 + t;
            int row = c >> 2;
            int kc = c & 3;
            uint4 va = *(const uint4*)(A + (size_t)(m0 + row) * K + k0 + kc * 8);
            *(uint4*)(As + row * LSTR + kc * 8) = va;
            uint4 vb = *(const uint4*)(Bm + (size_t)(n0 + row) * K + k0 + kc * 8);
            *(uint4*)(Bs + row * LSTR + kc * 8) = vb;
        }
        __syncthreads();
        bf16x8 af[4], bfr[4];
#pragma unroll
        for (int i = 0; i < 4; i++)
            af[i] = *(const bf16x8*)(As + (wm * 64 + i * 16 + l16) * LSTR + quad * 8);
#pragma unroll
        for (int j = 0; j < 4; j++)
            bfr[j] = *(const bf16x8*)(Bs + (wn * 64 + j * 16 + l16) * LSTR + quad * 8);
#pragma unroll
        for (int i = 0; i < 4; i++)
#pragma unroll
            for (int j = 0; j < 4; j++)
                acc[i][j] = __builtin_amdgcn_mfma_f32_16x16x32_bf16(
                    af[i], bfr[j], acc[i][j], 0, 0, 0);
        __syncthreads();
    }
    // epilogue: D[row=(lane>>4)*4+r][col=lane&15] per 16x16 tile
#pragma unroll
    for (int i = 0; i < 4; i++)
#pragma unroll
        for (int j = 0; j < 4; j++)
#pragma unroll
            for (int r = 0; r < 4; r++) {
                int row = m0 + wm * 64 + i * 16 + quad * 4 + r;
                int col = n0 + wn * 64 + j * 16 + l16;
                C[(size_t)row * N + col] = acc[i][j][r];
            }
}

// ---------------- sequential RNN scan ----------------
// 64 blocks (one per (b,h) chain), 64 threads (1 wave). Lane e owns output e.
// W row in registers, h in LDS (broadcast reads), fp32 throughout.
__global__ __launch_bounds__(64) void rnn_scan(
    const float* __restrict__ xp,      // [B,S,H,D] fp32 (GEMM1 output)
    const float* __restrict__ w_h,     // [H,D,D]
    const float* __restrict__ bias,    // [H,D]
    const float* __restrict__ h0,      // [B,H,D]
    unsigned short* __restrict__ y) {  // [B,S,H,D] bf16
    const int bh = blockIdx.x;
    const int b = bh >> 4;
    const int h = bh & 15;
    const int e = threadIdx.x;

    __shared__ __align__(16) float hs[64];

    // load W[h][e][0..63] into registers
    float Wr[64];
    const float* wrow = w_h + ((size_t)(h * 64 + e)) * 64;
#pragma unroll
    for (int q = 0; q < 16; q++) {
        float4 v = ((const float4*)wrow)[q];
        Wr[4 * q + 0] = v.x; Wr[4 * q + 1] = v.y;
        Wr[4 * q + 2] = v.z; Wr[4 * q + 3] = v.w;
    }
    const float be = bias[h * 64 + e];
    hs[e] = h0[(b * 16 + h) * 64 + e];

    const float* xb = xp + ((size_t)(b * S_) * 16 + h) * 64 + e;  // stride 1024/step
    unsigned short* yb = y + ((size_t)(b * S_) * 16 + h) * 64 + e;

    // 8-deep prefetch of x_t
    float xbuf[8];
#pragma unroll
    for (int p = 0; p < 8; p++) xbuf[p] = xb[p * 1024];

    const float4* h4 = (const float4*)hs;
    for (int t = 0; t < S_; t += 8) {
#pragma unroll
        for (int u = 0; u < 8; u++) {
            float xv = xbuf[u];
            int tn = t + u + 8;
            if (tn < S_) xbuf[u] = xb[tn * 1024];
            float a0 = 0.f, a1 = 0.f, a2 = 0.f, a3 = 0.f;
#pragma unroll
            for (int q = 0; q < 16; q++) {
                float4 v = h4[q];  // LDS broadcast, conflict-free
                a0 = fmaf(Wr[4 * q + 0], v.x, a0);
                a1 = fmaf(Wr[4 * q + 1], v.y, a1);
                a2 = fmaf(Wr[4 * q + 2], v.z, a2);
                a3 = fmaf(Wr[4 * q + 3], v.w, a3);
            }
            float pre = ((a0 + a1) + (a2 + a3)) + be + xv;
            // stable fast tanh: sign(x)*(1-e^{-2|x|})/(1+e^{-2|x|})
            float ax = fabsf(pre);
            float em = __expf(-2.0f * ax);
            float r = (1.0f - em) / (1.0f + em);
            float hn = copysignf(r, pre);
            // single wave: DS pipe is in-order per wave; aliasing keeps
            // this write ordered after this step's reads and before next reads
            hs[e] = hn;
            yb[(t + u) * 1024] = f2bf(hn);
        }
    }
}

extern "C" void kernel_launch(void* const* d_in, const int* in_sizes, int n_in,
                              void* d_out, int out_size, void* d_ws, size_t ws_size,
                              hipStream_t stream) {
    const float* x     = (const float*)d_in[0];  // [B,S,IN]
    const float* h0    = (const float*)d_in[1];  // [B,H,D]
    const float* w_in  = (const float*)d_in[2];  // [HD,IN]
    const float* w_h   = (const float*)d_in[3];  // [H,D,D]
    const float* bias  = (const float*)d_in[4];  // [H,D]
    const float* w_out = (const float*)d_in[5];  // [OUT,HD]
    float* out = (float*)d_out;                  // [B,S,OUT] fp32; doubles as xp scratch

    char* ws = (char*)d_ws;
    unsigned short* x_bf    = (unsigned short*)(ws);                       // 33.5 MB
    unsigned short* win_bf  = (unsigned short*)(ws + (size_t)33554432);    // 2 MB
    unsigned short* wout_bf = (unsigned short*)(ws + (size_t)35651584);    // 2 MB
    unsigned short* y_bf    = (unsigned short*)(ws + (size_t)37748736);    // 33.5 MB

    // casts
    {
        int n4 = (M_ * IN_) / 4;
        cast_f32_bf16<<<(n4 + 255) / 256, 256, 0, stream>>>(x, x_bf, n4);
        int w4 = (HD_ * IN_) / 4;
        cast_f32_bf16<<<(w4 + 255) / 256, 256, 0, stream>>>(w_in, win_bf, w4);
        cast_f32_bf16<<<(w4 + 255) / 256, 256, 0, stream>>>(w_out, wout_bf, w4);
    }
    // GEMM1: xp = x @ w_in^T  -> stored in d_out as scratch
    dim3 g1(HD_ / 128, M_ / 128);
    gemm_bt<<<g1, 256, 0, stream>>>(x_bf, win_bf, out, M_, HD_, IN_);
    // sequential scan: reads xp (d_out), writes y_bf
    rnn_scan<<<64, 64, 0, stream>>>(out, w_h, bias, h0, y_bf);
    // GEMM2: out = y @ w_out^T  -> overwrites d_out
    dim3 g2(OUT_ / 128, M_ / 128);
    gemm_bt<<<g2, 256, 0, stream>>>(y_bf, wout_bf, out, M_, OUT_, HD_);
}

// Round 2
// 1367.043 us; speedup vs baseline: 2.2930x; 2.2930x over previous
//
#include <hip/hip_runtime.h>

#define B_ 4
#define S_ 4096
#define IN_ 1024
#define H_ 16
#define D_ 64
#define OUT_ 1024
#define HD_ 1024   // H*D
#define M_ 16384   // B*S

typedef __bf16 bf16x8 __attribute__((ext_vector_type(8)));
typedef float floatx4 __attribute__((ext_vector_type(4)));
typedef float floatx2 __attribute__((ext_vector_type(2)));

static __device__ __forceinline__ unsigned short f2bf(float f) {
    unsigned int u = __builtin_bit_cast(unsigned int, f);
    u += 0x7fffu + ((u >> 16) & 1u);   // round-to-nearest-even
    return (unsigned short)(u >> 16);
}

// ---------------- cast fp32 -> bf16, vectorized x4 ----------------
__global__ void cast_f32_bf16(const float* __restrict__ src,
                              unsigned short* __restrict__ dst, int n4) {
    int i = blockIdx.x * blockDim.x + threadIdx.x;
    if (i < n4) {
        float4 v = ((const float4*)src)[i];
        ushort4 o;
        o.x = f2bf(v.x); o.y = f2bf(v.y); o.z = f2bf(v.z); o.w = f2bf(v.w);
        ((ushort4*)dst)[i] = o;
    }
}

// ---------------- bf16 MFMA GEMM: C[M,N] = A[M,K] * B[N,K]^T ----------------
#define LSTR 40
__global__ __launch_bounds__(256) void gemm_bt(
    const unsigned short* __restrict__ A,   // [M,K] bf16
    const unsigned short* __restrict__ Bm,  // [N,K] bf16
    float* __restrict__ C, int M, int N, int K) {
    __shared__ unsigned short As[128 * LSTR];
    __shared__ unsigned short Bs[128 * LSTR];
    const int t = threadIdx.x;
    const int lane = t & 63;
    const int wave = t >> 6;
    const int wm = wave >> 1, wn = wave & 1;
    const int m0 = blockIdx.y * 128;
    const int n0 = blockIdx.x * 128;
    const int l16 = lane & 15;
    const int quad = lane >> 4;

    floatx4 acc[4][4];
#pragma unroll
    for (int i = 0; i < 4; i++)
#pragma unroll
        for (int j = 0; j < 4; j++) acc[i][j] = (floatx4){0.f, 0.f, 0.f, 0.f};

    for (int k0 = 0; k0 < K; k0 += 32) {
#pragma unroll
        for (int it = 0; it < 2; it++) {
            int c = it * 256 + t;
            int row = c >> 2;
            int kc = c & 3;
            uint4 va = *(const uint4*)(A + (size_t)(m0 + row) * K + k0 + kc * 8);
            *(uint4*)(As + row * LSTR + kc * 8) = va;
            uint4 vb = *(const uint4*)(Bm + (size_t)(n0 + row) * K + k0 + kc * 8);
            *(uint4*)(Bs + row * LSTR + kc * 8) = vb;
        }
        __syncthreads();
        bf16x8 af[4], bfr[4];
#pragma unroll
        for (int i = 0; i < 4; i++)
            af[i] = *(const bf16x8*)(As + (wm * 64 + i * 16 + l16) * LSTR + quad * 8);
#pragma unroll
        for (int j = 0; j < 4; j++)
            bfr[j] = *(const bf16x8*)(Bs + (wn * 64 + j * 16 + l16) * LSTR + quad * 8);
#pragma unroll
        for (int i = 0; i < 4; i++)
#pragma unroll
            for (int j = 0; j < 4; j++)
                acc[i][j] = __builtin_amdgcn_mfma_f32_16x16x32_bf16(
                    af[i], bfr[j], acc[i][j], 0, 0, 0);
        __syncthreads();
    }
#pragma unroll
    for (int i = 0; i < 4; i++)
#pragma unroll
        for (int j = 0; j < 4; j++)
#pragma unroll
            for (int r = 0; r < 4; r++) {
                int row = m0 + wm * 64 + i * 16 + quad * 4 + r;
                int col = n0 + wn * 64 + j * 16 + l16;
                C[(size_t)row * N + col] = acc[i][j][r];
            }
}

// ---------------- sequential RNN scan (v2) ----------------
// 64 blocks (one (b,h) chain each), 1 wave. Lane e owns output e.
// v2: pk_fma (float2), rcp-based tanh, batched double-buffered x prefetch.
__global__ __launch_bounds__(64, 1) void rnn_scan(
    const float* __restrict__ xp,      // [B,S,H,D] fp32 (GEMM1 output)
    const float* __restrict__ w_h,     // [H,D,D]
    const float* __restrict__ bias,    // [H,D]
    const float* __restrict__ h0,      // [B,H,D]
    unsigned short* __restrict__ y) {  // [B,S,H,D] bf16
    const int bh = blockIdx.x;
    const int b = bh >> 4;
    const int h = bh & 15;
    const int e = threadIdx.x;

    __shared__ __align__(16) float hs[64];

    // W[h][e][0..63] as 32 packed float2 in VGPRs
    floatx2 W2[32];
    const float* wrow = w_h + ((size_t)(h * 64 + e)) * 64;
#pragma unroll
    for (int q = 0; q < 16; q++) {
        float4 v = ((const float4*)wrow)[q];
        W2[2 * q]     = (floatx2){v.x, v.y};
        W2[2 * q + 1] = (floatx2){v.z, v.w};
    }
    const float be = bias[h * 64 + e];
    hs[e] = h0[(b * 16 + h) * 64 + e];

    const float* xb = xp + ((size_t)(b * S_) * 16 + h) * 64 + e;  // stride 1024 floats/step
    unsigned short* yb = y + ((size_t)(b * S_) * 16 + h) * 64 + e;

    // two 8-deep x buffers, loaded in unconditional batches
    float xA[8], xB[8];
#pragma unroll
    for (int p = 0; p < 8; p++) xA[p] = xb[(size_t)p * 1024];
#pragma unroll
    for (int p = 0; p < 8; p++) xB[p] = xb[(size_t)(8 + p) * 1024];

    const float4* h4 = (const float4*)hs;

    auto step = [&](int t, float xv) {
        floatx2 a[8];
#pragma unroll
        for (int i = 0; i < 8; i++) a[i] = (floatx2){0.f, 0.f};
#pragma unroll
        for (int q = 0; q < 16; q++) {
            float4 v = h4[q];  // lane-invariant address -> LDS broadcast, conflict-free
            floatx2 lo = (floatx2){v.x, v.y};
            floatx2 hi = (floatx2){v.z, v.w};
            int ai = (q & 3) * 2;
            a[ai]     = __builtin_elementwise_fma(W2[2 * q],     lo, a[ai]);
            a[ai + 1] = __builtin_elementwise_fma(W2[2 * q + 1], hi, a[ai + 1]);
        }
        floatx2 s = ((a[0] + a[1]) + (a[2] + a[3])) + ((a[4] + a[5]) + (a[6] + a[7]));
        float pre = (s.x + s.y) + (be + xv);
        // tanh(pre) = sign * (1 - em) / (1 + em),  em = e^{-2|pre|}
        float ax = fabsf(pre);
        float em = __expf(-2.0f * ax);
        float r = (1.0f - em) * __builtin_amdgcn_rcpf(1.0f + em);  // v_rcp_f32, ~1 ulp
        float hn = copysignf(r, pre);
        hs[e] = hn;  // single wave: DS pipe is in-order per wave, no barrier needed
        yb[(size_t)t * 1024] = f2bf(hn);
    };

    for (int t0 = 0; t0 < S_; t0 += 16) {
        // phase A: consume xA (steps t0..t0+7)
#pragma unroll
        for (int u = 0; u < 8; u++) step(t0 + u, xA[u]);
        if (t0 + 16 < S_) {   // wave-uniform branch, no per-lane predication
#pragma unroll
            for (int p = 0; p < 8; p++) xA[p] = xb[(size_t)(t0 + 16 + p) * 1024];
        }
        // phase B: consume xB (steps t0+8..t0+15)
#pragma unroll
        for (int u = 0; u < 8; u++) step(t0 + 8 + u, xB[u]);
        if (t0 + 24 < S_) {
#pragma unroll
            for (int p = 0; p < 8; p++) xB[p] = xb[(size_t)(t0 + 24 + p) * 1024];
        }
    }
}

extern "C" void kernel_launch(void* const* d_in, const int* in_sizes, int n_in,
                              void* d_out, int out_size, void* d_ws, size_t ws_size,
                              hipStream_t stream) {
    const float* x     = (const float*)d_in[0];  // [B,S,IN]
    const float* h0    = (const float*)d_in[1];  // [B,H,D]
    const float* w_in  = (const float*)d_in[2];  // [HD,IN]
    const float* w_h   = (const float*)d_in[3];  // [H,D,D]
    const float* bias  = (const float*)d_in[4];  // [H,D]
    const float* w_out = (const float*)d_in[5];  // [OUT,HD]
    float* out = (float*)d_out;                  // [B,S,OUT] fp32; doubles as xp scratch

    char* ws = (char*)d_ws;
    unsigned short* x_bf    = (unsigned short*)(ws);                       // 33.5 MB
    unsigned short* win_bf  = (unsigned short*)(ws + (size_t)33554432);    // 2 MB
    unsigned short* wout_bf = (unsigned short*)(ws + (size_t)35651584);    // 2 MB
    unsigned short* y_bf    = (unsigned short*)(ws + (size_t)37748736);    // 33.5 MB

    {
        int n4 = (M_ * IN_) / 4;
        cast_f32_bf16<<<(n4 + 255) / 256, 256, 0, stream>>>(x, x_bf, n4);
        int w4 = (HD_ * IN_) / 4;
        cast_f32_bf16<<<(w4 + 255) / 256, 256, 0, stream>>>(w_in, win_bf, w4);
        cast_f32_bf16<<<(w4 + 255) / 256, 256, 0, stream>>>(w_out, wout_bf, w4);
    }
    // GEMM1: xp = x @ w_in^T  -> stored in d_out as scratch
    dim3 g1(HD_ / 128, M_ / 128);
    gemm_bt<<<g1, 256, 0, stream>>>(x_bf, win_bf, out, M_, HD_, IN_);
    // sequential scan: reads xp (d_out), writes y_bf
    rnn_scan<<<64, 64, 0, stream>>>(out, w_h, bias, h0, y_bf);
    // GEMM2: out = y @ w_out^T  -> overwrites d_out
    dim3 g2(OUT_ / 128, M_ / 128);
    gemm_bt<<<g2, 256, 0, stream>>>(y_bf, wout_bf, out, M_, OUT_, HD_);
}

// Round 3
// 1093.294 us; speedup vs baseline: 2.8671x; 1.2504x over previous
//
#include <hip/hip_runtime.h>

#define B_ 4
#define S_ 4096
#define IN_ 1024
#define H_ 16
#define D_ 64
#define OUT_ 1024
#define HD_ 1024   // H*D
#define M_ 16384   // B*S

typedef __bf16 bf16x8 __attribute__((ext_vector_type(8)));
typedef float floatx4 __attribute__((ext_vector_type(4)));
typedef float floatx2 __attribute__((ext_vector_type(2)));

static __device__ __forceinline__ unsigned short f2bf(float f) {
    unsigned int u = __builtin_bit_cast(unsigned int, f);
    u += 0x7fffu + ((u >> 16) & 1u);   // round-to-nearest-even
    return (unsigned short)(u >> 16);
}

// quad_perm butterfly add via DPP (pure VALU, no LDS)
template <int CTRL>
static __device__ __forceinline__ float qadd(float v) {
    int s = __builtin_amdgcn_update_dpp(0, __builtin_bit_cast(int, v),
                                        CTRL, 0xF, 0xF, true);
    return v + __builtin_bit_cast(float, s);
}

// ---------------- cast fp32 -> bf16, vectorized x4 ----------------
__global__ void cast_f32_bf16(const float* __restrict__ src,
                              unsigned short* __restrict__ dst, int n4) {
    int i = blockIdx.x * blockDim.x + threadIdx.x;
    if (i < n4) {
        float4 v = ((const float4*)src)[i];
        ushort4 o;
        o.x = f2bf(v.x); o.y = f2bf(v.y); o.z = f2bf(v.z); o.w = f2bf(v.w);
        ((ushort4*)dst)[i] = o;
    }
}

// ---------------- bf16 MFMA GEMM: C[M,N] = A[M,K] * B[N,K]^T ----------------
#define LSTR 40
__global__ __launch_bounds__(256) void gemm_bt(
    const unsigned short* __restrict__ A,   // [M,K] bf16
    const unsigned short* __restrict__ Bm,  // [N,K] bf16
    float* __restrict__ C, int M, int N, int K) {
    __shared__ unsigned short As[128 * LSTR];
    __shared__ unsigned short Bs[128 * LSTR];
    const int t = threadIdx.x;
    const int lane = t & 63;
    const int wave = t >> 6;
    const int wm = wave >> 1, wn = wave & 1;
    const int m0 = blockIdx.y * 128;
    const int n0 = blockIdx.x * 128;
    const int l16 = lane & 15;
    const int quad = lane >> 4;

    floatx4 acc[4][4];
#pragma unroll
    for (int i = 0; i < 4; i++)
#pragma unroll
        for (int j = 0; j < 4; j++) acc[i][j] = (floatx4){0.f, 0.f, 0.f, 0.f};

    for (int k0 = 0; k0 < K; k0 += 32) {
#pragma unroll
        for (int it = 0; it < 2; it++) {
            int c = it * 256 + t;
            int row = c >> 2;
            int kc = c & 3;
            uint4 va = *(const uint4*)(A + (size_t)(m0 + row) * K + k0 + kc * 8);
            *(uint4*)(As + row * LSTR + kc * 8) = va;
            uint4 vb = *(const uint4*)(Bm + (size_t)(n0 + row) * K + k0 + kc * 8);
            *(uint4*)(Bs + row * LSTR + kc * 8) = vb;
        }
        __syncthreads();
        bf16x8 af[4], bfr[4];
#pragma unroll
        for (int i = 0; i < 4; i++)
            af[i] = *(const bf16x8*)(As + (wm * 64 + i * 16 + l16) * LSTR + quad * 8);
#pragma unroll
        for (int j = 0; j < 4; j++)
            bfr[j] = *(const bf16x8*)(Bs + (wn * 64 + j * 16 + l16) * LSTR + quad * 8);
#pragma unroll
        for (int i = 0; i < 4; i++)
#pragma unroll
            for (int j = 0; j < 4; j++)
                acc[i][j] = __builtin_amdgcn_mfma_f32_16x16x32_bf16(
                    af[i], bfr[j], acc[i][j], 0, 0, 0);
        __syncthreads();
    }
#pragma unroll
    for (int i = 0; i < 4; i++)
#pragma unroll
        for (int j = 0; j < 4; j++)
#pragma unroll
            for (int r = 0; r < 4; r++) {
                int row = m0 + wm * 64 + i * 16 + quad * 4 + r;
                int col = n0 + wn * 64 + j * 16 + l16;
                C[(size_t)row * N + col] = acc[i][j][r];
            }
}

// ---------------- sequential RNN scan (v3: 4 waves/chain) ----------------
// 64 blocks (one (b,h) chain), 256 threads = 4 waves on the 4 SIMDs of a CU.
// Wave w owns outputs e in [16w,16w+16); lane l: eo=l>>2, p=l&3 covers
// h[16p..16p+16). Quad DPP butterfly reduces the 4 partial sums; h lives in
// double-buffered LDS; one raw s_barrier per step (NO vmcnt drain, so the
// x prefetch and y stores stay in flight across steps).
__global__ __launch_bounds__(256, 1) void rnn_scan(
    const float* __restrict__ xp,      // [B,S,H,D] fp32 (GEMM1 output)
    const float* __restrict__ w_h,     // [H,D,D]
    const float* __restrict__ bias,    // [H,D]
    const float* __restrict__ h0,      // [B,H,D]
    unsigned short* __restrict__ y) {  // [B,S,H,D] bf16
    const int bh = blockIdx.x;
    const int b = bh >> 4;
    const int h = bh & 15;
    const int tid = threadIdx.x;
    const int w = tid >> 6;
    const int l = tid & 63;
    const int eo = l >> 2;
    const int p = l & 3;
    const int e = w * 16 + eo;

    __shared__ __align__(16) float hbuf[2][64];

    // W[e][16p..16p+16) as 8 packed float2
    floatx2 W2[8];
    const float* wrow = w_h + ((size_t)(h * 64 + e)) * 64 + p * 16;
#pragma unroll
    for (int q = 0; q < 4; q++) {
        float4 v = ((const float4*)wrow)[q];
        W2[2 * q]     = (floatx2){v.x, v.y};
        W2[2 * q + 1] = (floatx2){v.z, v.w};
    }
    const float be = bias[h * 64 + e];
    if (tid < 64) hbuf[0][tid] = h0[(b * 16 + h) * 64 + tid];
    __syncthreads();

    const float* xb = xp + ((size_t)(b * S_) * 16 + h) * 64 + e;  // + t*1024
    unsigned short* yb = y + ((size_t)(b * S_) * 16 + h) * 64 + e;

    float xA[8], xB[8];
#pragma unroll
    for (int i2 = 0; i2 < 8; i2++) xA[i2] = xb[(size_t)i2 * 1024];
#pragma unroll
    for (int i2 = 0; i2 < 8; i2++) xB[i2] = xb[(size_t)(8 + i2) * 1024];

    auto step = [&](int r, int t, float xv) {
        const float4* h4 = (const float4*)(hbuf[r] + p * 16);
        float4 v0 = h4[0], v1 = h4[1], v2 = h4[2], v3 = h4[3];
        floatx2 z = (floatx2){0.f, 0.f};
        floatx2 a0 = __builtin_elementwise_fma(W2[0], (floatx2){v0.x, v0.y}, z);
        floatx2 a1 = __builtin_elementwise_fma(W2[1], (floatx2){v0.z, v0.w}, z);
        floatx2 a2 = __builtin_elementwise_fma(W2[2], (floatx2){v1.x, v1.y}, z);
        floatx2 a3 = __builtin_elementwise_fma(W2[3], (floatx2){v1.z, v1.w}, z);
        a0 = __builtin_elementwise_fma(W2[4], (floatx2){v2.x, v2.y}, a0);
        a1 = __builtin_elementwise_fma(W2[5], (floatx2){v2.z, v2.w}, a1);
        a2 = __builtin_elementwise_fma(W2[6], (floatx2){v3.x, v3.y}, a2);
        a3 = __builtin_elementwise_fma(W2[7], (floatx2){v3.z, v3.w}, a3);
        floatx2 s2 = (a0 + a1) + (a2 + a3);
        float sum = s2.x + s2.y;
        sum = qadd<0xB1>(sum);   // quad_perm [1,0,3,2]
        sum = qadd<0x4E>(sum);   // quad_perm [2,3,0,1] -> all 4 lanes have total
        float pre = (sum + be) + xv;
        // tanh: em = 2^(-2*log2e*|pre|); hn = sign * (1-em)/(1+em)
        float em = __builtin_amdgcn_exp2f(fabsf(pre) * -2.885390081777927f);
        float rr = (1.0f - em) * __builtin_amdgcn_rcpf(1.0f + em);
        float hn = copysignf(rr, pre);
        if (p == 0) {
            hbuf[1 - r][e] = hn;
            yb[(size_t)t * 1024] = f2bf(hn);
        }
        // raw barrier: own DS ops retired (lgkmcnt(0)), then sync waves.
        // Deliberately NOT __syncthreads(): no vmcnt(0) drain, so global
        // prefetch loads / y stores stay outstanding across steps.
        asm volatile("s_waitcnt lgkmcnt(0)\n\ts_barrier" ::: "memory");
    };

    for (int t0 = 0; t0 < S_; t0 += 16) {
#pragma unroll
        for (int u = 0; u < 8; u++) step(u & 1, t0 + u, xA[u]);
        if (t0 + 16 < S_) {
#pragma unroll
            for (int i2 = 0; i2 < 8; i2++) xA[i2] = xb[(size_t)(t0 + 16 + i2) * 1024];
        }
#pragma unroll
        for (int u = 0; u < 8; u++) step(u & 1, t0 + 8 + u, xB[u]);
        if (t0 + 24 < S_) {
#pragma unroll
            for (int i2 = 0; i2 < 8; i2++) xB[i2] = xb[(size_t)(t0 + 24 + i2) * 1024];
        }
    }
}

extern "C" void kernel_launch(void* const* d_in, const int* in_sizes, int n_in,
                              void* d_out, int out_size, void* d_ws, size_t ws_size,
                              hipStream_t stream) {
    const float* x     = (const float*)d_in[0];  // [B,S,IN]
    const float* h0    = (const float*)d_in[1];  // [B,H,D]
    const float* w_in  = (const float*)d_in[2];  // [HD,IN]
    const float* w_h   = (const float*)d_in[3];  // [H,D,D]
    const float* bias  = (const float*)d_in[4];  // [H,D]
    const float* w_out = (const float*)d_in[5];  // [OUT,HD]
    float* out = (float*)d_out;                  // [B,S,OUT] fp32; doubles as xp scratch

    char* ws = (char*)d_ws;
    unsigned short* x_bf    = (unsigned short*)(ws);                       // 33.5 MB
    unsigned short* win_bf  = (unsigned short*)(ws + (size_t)33554432);    // 2 MB
    unsigned short* wout_bf = (unsigned short*)(ws + (size_t)35651584);    // 2 MB
    unsigned short* y_bf    = (unsigned short*)(ws + (size_t)37748736);    // 33.5 MB

    {
        int n4 = (M_ * IN_) / 4;
        cast_f32_bf16<<<(n4 + 255) / 256, 256, 0, stream>>>(x, x_bf, n4);
        int w4 = (HD_ * IN_) / 4;
        cast_f32_bf16<<<(w4 + 255) / 256, 256, 0, stream>>>(w_in, win_bf, w4);
        cast_f32_bf16<<<(w4 + 255) / 256, 256, 0, stream>>>(w_out, wout_bf, w4);
    }
    // GEMM1: xp = x @ w_in^T  -> stored in d_out as scratch
    dim3 g1(HD_ / 128, M_ / 128);
    gemm_bt<<<g1, 256, 0, stream>>>(x_bf, win_bf, out, M_, HD_, IN_);
    // sequential scan: reads xp (d_out), writes y_bf
    rnn_scan<<<64, 256, 0, stream>>>(out, w_h, bias, h0, y_bf);
    // GEMM2: out = y @ w_out^T  -> overwrites d_out
    dim3 g2(OUT_ / 128, M_ / 128);
    gemm_bt<<<g2, 256, 0, stream>>>(y_bf, wout_bf, out, M_, OUT_, HD_);
}